// Round 1
// baseline (289.173 us; speedup 1.0000x reference)
//
#include <hip/hip_runtime.h>

// ---------------------------------------------------------------------------
// Swin-3D shifted window attention, MI355X (gfx950)
// x:(2,16,56,56,128) f32; WIN=(8,7,7) SHIFT=(4,3,3) HEADS=4 HD=32 VOL=392
// Kernel A: per (window,head): QKV (mfma bf16) -> LDS, attention -> ws (bf16)
// Kernel B: per window: proj (mfma bf16) + scatter with inverse roll -> out f32
// ---------------------------------------------------------------------------

#define DIMC   128
#define HEADS  4
#define HD     32
#define VOL    392
#define VPAD   416          // 26 tiles of 16
#define NWIN_B 128          // windows per batch
#define SCALE  0.17677669529663687f   // 1/sqrt(32)

typedef __bf16 bf16;
typedef __attribute__((ext_vector_type(8))) __bf16 bf16x8;
typedef __attribute__((ext_vector_type(4))) float  f32x4;

// LDS budget for kernel A
#define SM_Q    (VPAD*HD)                 // bf16 elements
#define SM_K    (VPAD*HD)
#define SM_VT   (HD*VPAD)
#define SMEM_A  (SM_Q*2 + SM_K*2 + SM_VT*2 + 2560*4 + 4*16*32*2)  // = 94208 B

static __device__ inline bf16x8 pack8(float4 a, float4 b) {
    bf16x8 r;
    r[0] = (bf16)a.x; r[1] = (bf16)a.y; r[2] = (bf16)a.z; r[3] = (bf16)a.w;
    r[4] = (bf16)b.x; r[5] = (bf16)b.y; r[6] = (bf16)b.z; r[7] = (bf16)b.w;
    return r;
}

static __device__ inline bf16x8 zero8() {
    bf16x8 z;
#pragma unroll
    for (int i = 0; i < 8; ++i) z[i] = (bf16)0.0f;
    return z;
}

// region label in SHIFTED coords (matches reference _attn_mask)
static __device__ inline int region_label(int ts, int hs, int wsc) {
    const int dl = ts  < 8  ? 0 : (ts  < 12 ? 1 : 2);
    const int hl = hs  < 49 ? 0 : (hs  < 53 ? 1 : 2);
    const int wl = wsc < 49 ? 0 : (wsc < 53 ? 1 : 2);
    return dl * 9 + hl * 3 + wl;
}

__global__ __launch_bounds__(256, 1) void swin_qkv_attn(
    const float* __restrict__ x, const float* __restrict__ wqkv,
    const float* __restrict__ bqkv, const float* __restrict__ btab,
    bf16* __restrict__ aw)
{
    const int head = blockIdx.x & 3;
    const int win  = blockIdx.x >> 2;      // 0..255
    const int b    = win >> 7;
    const int wrem = win & 127;
    const int it   = wrem >> 6;            // 0..1
    const int ih   = (wrem >> 3) & 7;      // 0..7
    const int iw   = wrem & 7;             // 0..7

    const int tid  = threadIdx.x;
    const int lane = tid & 63;
    const int wv   = tid >> 6;             // wave 0..3
    const int l16  = lane & 15;
    const int lg   = lane >> 4;            // 0..3

    extern __shared__ char smem[];
    bf16*  q_lds    = (bf16*)smem;                     // [VPAD][32]
    bf16*  k_lds    = q_lds + SM_Q;                    // [VPAD][32]
    bf16*  vT_lds   = k_lds + SM_K;                    // [32][VPAD]
    float* bias_lds = (float*)(vT_lds + SM_VT);        // [2535]
    bf16*  pstage   = (bf16*)(bias_lds + 2560);        // [4][16][32]
    bf16*  pst      = pstage + wv * (16 * 32);

    // stage this head's column of the relative-position bias table
    for (int i = tid; i < 2535; i += 256) bias_lds[i] = btab[i * HEADS + head];

    // ---------------- phase 1: QKV -> LDS ----------------
    for (int mt = wv; mt < 26; mt += 4) {
        bf16x8 af[4];
        {
            const int tv = mt * 16 + l16;   // A-frag row = lane&15
            if (tv < VOL) {
                const int lt = tv / 49, rr = tv - lt * 49;
                const int lh = rr / 7,  lw = rr - lh * 7;
                const int t0 = (it * 8 + lt + 4) & 15;
                int h0 = ih * 7 + lh + 3; if (h0 >= 56) h0 -= 56;
                int w0 = iw * 7 + lw + 3; if (w0 >= 56) w0 -= 56;
                const float* xp = x + (size_t)(((b * 16 + t0) * 56 + h0) * 56 + w0) * DIMC + 8 * lg;
#pragma unroll
                for (int ks = 0; ks < 4; ++ks) {
                    float4 u0 = *(const float4*)(xp + ks * 32);
                    float4 u1 = *(const float4*)(xp + ks * 32 + 4);
                    af[ks] = pack8(u0, u1);
                }
            } else {
#pragma unroll
                for (int ks = 0; ks < 4; ++ks) af[ks] = zero8();
            }
        }
#pragma unroll
        for (int nt = 0; nt < 6; ++nt) {
            const int g    = nt >> 1;                // 0=q 1=k 2=v
            const int colw = (nt & 1) * 16 + l16;    // 0..31 within head slice
            const int wrow = g * DIMC + head * HD + colw;
            const float* wp = wqkv + (size_t)wrow * DIMC + 8 * lg;
            f32x4 acc = {0.f, 0.f, 0.f, 0.f};
#pragma unroll
            for (int ks = 0; ks < 4; ++ks) {
                float4 u0 = *(const float4*)(wp + ks * 32);
                float4 u1 = *(const float4*)(wp + ks * 32 + 4);
                acc = __builtin_amdgcn_mfma_f32_16x16x32_bf16(af[ks], pack8(u0, u1), acc, 0, 0, 0);
            }
            const float bv = bqkv[wrow];
#pragma unroll
            for (int r = 0; r < 4; ++r) {
                const int row = mt * 16 + lg * 4 + r;   // C row = (lane>>4)*4+reg
                const float v = acc[r] + bv;
                if (g == 0)      q_lds[row * HD + colw]   = (bf16)(v * SCALE);
                else if (g == 1) k_lds[row * HD + colw]   = (bf16)v;
                else             vT_lds[colw * VPAD + row] = (bf16)v;
            }
        }
    }
    __syncthreads();

    // ---------------- phase 2: attention ----------------
    for (int mt = wv; mt < 25; mt += 4) {
        const bf16x8 qf = *(const bf16x8*)&q_lds[(mt * 16 + l16) * HD + 8 * lg];
        f32x4 s[26];
#pragma unroll
        for (int nt = 0; nt < 26; ++nt) {
            const bf16x8 kf = *(const bf16x8*)&k_lds[(nt * 16 + l16) * HD + 8 * lg];
            f32x4 z = {0.f, 0.f, 0.f, 0.f};
            s[nt] = __builtin_amdgcn_mfma_f32_16x16x32_bf16(qf, kf, z, 0, 0, 0);
        }
        // per-reg query coords/labels
        int qt4[4], qh4[4], qw4[4], lq4[4];
#pragma unroll
        for (int r = 0; r < 4; ++r) {
            int q = mt * 16 + lg * 4 + r; if (q >= VOL) q = 0;
            const int qt = q / 49, rr = q - qt * 49;
            const int qh = rr / 7, qw = rr - qh * 7;
            qt4[r] = qt; qh4[r] = qh; qw4[r] = qw;
            lq4[r] = region_label(it * 8 + qt, ih * 7 + qh, iw * 7 + qw);
        }
        float mx[4] = {-1e30f, -1e30f, -1e30f, -1e30f};
#pragma unroll
        for (int nt = 0; nt < 26; ++nt) {
            const int kv  = nt * 16 + l16;            // C col = lane&15
            const bool kok = kv < VOL;
            const int k2 = kok ? kv : 0;
            const int kt = k2 / 49, rr = k2 - kt * 49;
            const int kh = rr / 7,  kw = rr - kh * 7;
            const int lk = region_label(it * 8 + kt, ih * 7 + kh, iw * 7 + kw);
#pragma unroll
            for (int r = 0; r < 4; ++r) {
                float v = -1e30f;
                if (kok) {
                    const int rel = ((qt4[r] - kt + 7) * 13 + (qh4[r] - kh + 6)) * 13 + (qw4[r] - kw + 6);
                    v = s[nt][r] + bias_lds[rel] + (lq4[r] == lk ? 0.f : -100.f);
                }
                s[nt][r] = v;
                mx[r] = fmaxf(mx[r], v);
            }
        }
#pragma unroll
        for (int off = 1; off < 16; off <<= 1) {
#pragma unroll
            for (int r = 0; r < 4; ++r) mx[r] = fmaxf(mx[r], __shfl_xor(mx[r], off, 64));
        }
        float sm[4] = {0.f, 0.f, 0.f, 0.f};
#pragma unroll
        for (int nt = 0; nt < 26; ++nt) {
#pragma unroll
            for (int r = 0; r < 4; ++r) {
                const float e = __expf(s[nt][r] - mx[r]);
                s[nt][r] = e; sm[r] += e;
            }
        }
#pragma unroll
        for (int off = 1; off < 16; off <<= 1) {
#pragma unroll
            for (int r = 0; r < 4; ++r) sm[r] += __shfl_xor(sm[r], off, 64);
        }
        float inv[4];
#pragma unroll
        for (int r = 0; r < 4; ++r) inv[r] = 1.0f / sm[r];

        // PV: 13 chunks of 32 tokens through per-wave P staging
        f32x4 o0 = {0.f, 0.f, 0.f, 0.f}, o1 = {0.f, 0.f, 0.f, 0.f};
#pragma unroll
        for (int ch = 0; ch < 13; ++ch) {
#pragma unroll
            for (int sub = 0; sub < 2; ++sub) {
#pragma unroll
                for (int r = 0; r < 4; ++r)
                    pst[(lg * 4 + r) * 32 + sub * 16 + l16] = (bf16)(s[2 * ch + sub][r] * inv[r]);
            }
            asm volatile("s_waitcnt lgkmcnt(0)" ::: "memory");
            const bf16x8 pf = *(const bf16x8*)&pst[l16 * 32 + 8 * lg];
            const bf16x8 v0 = *(const bf16x8*)&vT_lds[(l16)      * VPAD + ch * 32 + 8 * lg];
            const bf16x8 v1 = *(const bf16x8*)&vT_lds[(16 + l16) * VPAD + ch * 32 + 8 * lg];
            o0 = __builtin_amdgcn_mfma_f32_16x16x32_bf16(pf, v0, o0, 0, 0, 0);
            o1 = __builtin_amdgcn_mfma_f32_16x16x32_bf16(pf, v1, o1, 0, 0, 0);
        }
#pragma unroll
        for (int r = 0; r < 4; ++r) {
            const int q = mt * 16 + lg * 4 + r;
            if (q < VOL) {
                bf16* op = aw + ((size_t)win * VPAD + q) * DIMC + head * HD;
                op[l16]      = (bf16)o0[r];
                op[16 + l16] = (bf16)o1[r];
            }
        }
    }
}

__global__ __launch_bounds__(256, 1) void swin_proj(
    const bf16* __restrict__ aw, const float* __restrict__ wproj,
    const float* __restrict__ bproj, float* __restrict__ out)
{
    const int win  = blockIdx.x;
    const int b    = win >> 7;
    const int wrem = win & 127;
    const int it   = wrem >> 6;
    const int ih   = (wrem >> 3) & 7;
    const int iw   = wrem & 7;

    const int tid  = threadIdx.x;
    const int lane = tid & 63;
    const int wv   = tid >> 6;
    const int l16  = lane & 15;
    const int lg   = lane >> 4;

    for (int mt = wv; mt < 25; mt += 4) {
        bf16x8 af[4];
        const bf16* ap = aw + ((size_t)win * VPAD + mt * 16 + l16) * DIMC + 8 * lg;
#pragma unroll
        for (int ks = 0; ks < 4; ++ks) af[ks] = *(const bf16x8*)(ap + ks * 32);

        float* ob[4]; bool qok[4];
#pragma unroll
        for (int r = 0; r < 4; ++r) {
            int q = mt * 16 + lg * 4 + r;
            qok[r] = q < VOL; if (!qok[r]) q = 0;
            const int lt = q / 49, rr = q - lt * 49;
            const int lh = rr / 7, lw = rr - lh * 7;
            const int t0 = (it * 8 + lt + 4) & 15;
            int h0 = ih * 7 + lh + 3; if (h0 >= 56) h0 -= 56;
            int w0 = iw * 7 + lw + 3; if (w0 >= 56) w0 -= 56;
            ob[r] = out + (size_t)(((b * 16 + t0) * 56 + h0) * 56 + w0) * DIMC;
        }
#pragma unroll
        for (int nt = 0; nt < 8; ++nt) {
            f32x4 acc = {0.f, 0.f, 0.f, 0.f};
            const float* wp = wproj + (size_t)(nt * 16 + l16) * DIMC + 8 * lg;
#pragma unroll
            for (int ks = 0; ks < 4; ++ks) {
                float4 u0 = *(const float4*)(wp + ks * 32);
                float4 u1 = *(const float4*)(wp + ks * 32 + 4);
                acc = __builtin_amdgcn_mfma_f32_16x16x32_bf16(af[ks], pack8(u0, u1), acc, 0, 0, 0);
            }
            const float bv = bproj[nt * 16 + l16];
#pragma unroll
            for (int r = 0; r < 4; ++r)
                if (qok[r]) ob[r][nt * 16 + l16] = acc[r] + bv;
        }
    }
}

extern "C" void kernel_launch(void* const* d_in, const int* in_sizes, int n_in,
                              void* d_out, int out_size, void* d_ws, size_t ws_size,
                              hipStream_t stream) {
    const float* x     = (const float*)d_in[0];
    const float* wqkv  = (const float*)d_in[1];
    const float* bqkv  = (const float*)d_in[2];
    const float* wproj = (const float*)d_in[3];
    const float* bproj = (const float*)d_in[4];
    const float* btab  = (const float*)d_in[5];
    bf16* aw   = (bf16*)d_ws;          // needs 256*416*128*2 = 27.3 MB
    float* out = (float*)d_out;

    // allow >64KB dynamic LDS (defensive; ignore error)
    (void)hipFuncSetAttribute((const void*)swin_qkv_attn,
                              hipFuncAttributeMaxDynamicSharedMemorySize, SMEM_A);

    swin_qkv_attn<<<dim3(256 * HEADS), dim3(256), SMEM_A, stream>>>(x, wqkv, bqkv, btab, aw);
    swin_proj<<<dim3(256), dim3(256), 0, stream>>>(aw, wproj, bproj, out);
}

// Round 3
// 163.698 us; speedup vs baseline: 1.7665x; 1.7665x over previous
//
#include <hip/hip_runtime.h>

// ---------------------------------------------------------------------------
// Swin-3D shifted window attention, MI355X (gfx950)
// R3: R2 (S^T formulation, bias+mask table as MFMA C-init, XOR-swizzled LDS,
//     hoisted W frags, 79.5 KB LDS -> 2 blocks/CU) + fix: phase-1 covers all
//     26 tiles so swizzled V^T slots for tv in [400,416) are initialized
//     (0 x NaN = NaN was poisoning the PV accumulator), + restored lgkmcnt
//     wait between P-stage write/read.
// ---------------------------------------------------------------------------

#define DIMC   128
#define HEADS  4
#define HD     32
#define VOL    392
#define VPAD   416
#define TQ     400
#define TK     416
#define SCALE  0.17677669529663687f   // 1/sqrt(32)

typedef __bf16 bf16;
typedef __attribute__((ext_vector_type(8))) __bf16 bf16x8;
typedef __attribute__((ext_vector_type(4))) __bf16 bf16x4;
typedef __attribute__((ext_vector_type(4))) float  f32x4;

// LDS layout (elements of bf16)
#define QROWS   392
#define VTCOLS  416
#define PSTR    36
#define OFF_Q   0
#define OFF_K   (QROWS * 32)
#define OFF_VT  (2 * QROWS * 32)
#define OFF_PST (2 * QROWS * 32 + 32 * VTCOLS)
#define LDS_ELEMS (2 * QROWS * 32 + 32 * VTCOLS + 4 * 16 * PSTR)
#define SMEM_A  (LDS_ELEMS * 2)     // 81408 B -> 2 blocks/CU (<= 163840/2)

#define AW_BYTES (256ull * VPAD * DIMC * 2ull)   // 27.26 MB

static __device__ inline bf16x8 pack8(float4 a, float4 b) {
    bf16x8 r;
    r[0] = (bf16)a.x; r[1] = (bf16)a.y; r[2] = (bf16)a.z; r[3] = (bf16)a.w;
    r[4] = (bf16)b.x; r[5] = (bf16)b.y; r[6] = (bf16)b.z; r[7] = (bf16)b.w;
    return r;
}
static __device__ inline bf16x8 zero8() {
    bf16x8 z;
#pragma unroll
    for (int i = 0; i < 8; ++i) z[i] = (bf16)0.0f;
    return z;
}
static __device__ inline bf16x8 cat8(bf16x4 a, bf16x4 b) {
    bf16x8 r;
#pragma unroll
    for (int i = 0; i < 4; ++i) { r[i] = a[i]; r[4 + i] = b[i]; }
    return r;
}
// per-row XOR swizzle (on element index, 8-element = 16B granules)
static __device__ inline int swz4(int row) { return ((row >> 1) ^ (row >> 3)) & 3; }

// ---------------------------------------------------------------------------
// bias+mask table: tbl[pat][head][q(400)][k(416)] bf16
// pat = (t_boundary<<2)|(h_boundary<<1)|w_boundary
// ---------------------------------------------------------------------------
__global__ __launch_bounds__(256) void gen_table(const float* __restrict__ btab,
                                                 bf16* __restrict__ tbl) {
    const int idx = blockIdx.x * 256 + threadIdx.x;
    const int total = 8 * HEADS * TQ * (TK / 4);
    if (idx >= total) return;
    const int k4  = (idx % (TK / 4)) * 4;
    const int q   = (idx / (TK / 4)) % TQ;
    const int h   = (idx / ((TK / 4) * TQ)) & 3;
    const int pat = idx / ((TK / 4) * TQ * HEADS);
    const int tb = (pat >> 2) & 1, hb = (pat >> 1) & 1, wb = pat & 1;

    int qt = 0, qh = 0, qw = 0, lq = 0;
    if (q < VOL) {
        qt = q / 49; const int qr = q - qt * 49; qh = qr / 7; qw = qr - qh * 7;
        lq = (tb ? (qt < 4 ? 1 : 2) : 0) * 9 + (hb ? (qh < 4 ? 1 : 2) : 0) * 3 +
             (wb ? (qw < 4 ? 1 : 2) : 0);
    }
    bf16x4 out;
#pragma unroll
    for (int j = 0; j < 4; ++j) {
        const int k = k4 + j;
        float v;
        if (k >= VOL)      v = -30000.0f;
        else if (q >= VOL) v = 0.0f;
        else {
            const int kt = k / 49; const int kr = k - kt * 49;
            const int kh = kr / 7; const int kw = kr - kh * 7;
            const int rel = ((qt - kt + 7) * 13 + (qh - kh + 6)) * 13 + (qw - kw + 6);
            v = btab[rel * HEADS + h];
            const int lk = (tb ? (kt < 4 ? 1 : 2) : 0) * 9 +
                           (hb ? (kh < 4 ? 1 : 2) : 0) * 3 +
                           (wb ? (kw < 4 ? 1 : 2) : 0);
            if (lq != lk) v += -100.0f;
        }
        out[j] = (bf16)v;
    }
    *(bf16x4*)&tbl[((size_t)(pat * HEADS + h) * TQ + q) * TK + k4] = out;
}

// ---------------------------------------------------------------------------
// Kernel A: per (window,head): QKV -> LDS, attention (S^T path) -> aw (bf16)
// ---------------------------------------------------------------------------
__global__ __launch_bounds__(256, 2) void swin_attn(
    const float* __restrict__ x, const float* __restrict__ wqkv,
    const float* __restrict__ bqkv, const bf16* __restrict__ tbl,
    bf16* __restrict__ aw)
{
    const int head = blockIdx.x & 3;
    const int win  = blockIdx.x >> 2;      // 0..255
    const int b    = win >> 7;
    const int wrem = win & 127;
    const int it   = wrem >> 6;            // 0..1
    const int ih   = (wrem >> 3) & 7;      // 0..7
    const int iw   = wrem & 7;             // 0..7
    const int pat  = ((it == 1) ? 4 : 0) | ((ih == 7) ? 2 : 0) | ((iw == 7) ? 1 : 0);

    const int tid  = threadIdx.x;
    const int lane = tid & 63;
    const int wv   = tid >> 6;             // wave 0..3
    const int l16  = lane & 15;
    const int lg   = lane >> 4;            // 0..3

    extern __shared__ char smem[];
    bf16* lds = (bf16*)smem;
    bf16* pst = lds + OFF_PST + wv * (16 * PSTR);

    const bf16* tblh = tbl + (size_t)(pat * HEADS + head) * (TQ * TK);

    // ---- hoisted W fragments: o = g*2+h2, g: 0=Q 1=K 2=V ----
    bf16x8 wfr[6][4];
    float  bcol[4];
#pragma unroll
    for (int o = 0; o < 6; ++o) {
        const int g = o >> 1, h2 = o & 1;
        const int wrow = g * DIMC + head * HD + h2 * 16 + l16;
        const float* wp = wqkv + (size_t)wrow * DIMC + 8 * lg;
#pragma unroll
        for (int ks = 0; ks < 4; ++ks)
            wfr[o][ks] = pack8(*(const float4*)(wp + ks * 32),
                               *(const float4*)(wp + ks * 32 + 4));
        if (o < 4) bcol[o] = bqkv[wrow];
    }
    float bvr[2][4];
#pragma unroll
    for (int h2 = 0; h2 < 2; ++h2)
#pragma unroll
        for (int r = 0; r < 4; ++r)
            bvr[h2][r] = bqkv[2 * DIMC + head * HD + h2 * 16 + lg * 4 + r];

    // ------- phase 1: Q,K (row-token layout), V^T -> LDS (ALL 26 tiles) ----
    for (int mt = wv; mt < 26; mt += 4) {
        const int tv = mt * 16 + l16;      // token for A/B x-fragment (<= 415)
        bf16x8 af[4];
        if (tv < VOL) {
            const int lt = tv / 49, rr = tv - lt * 49;
            const int lh = rr / 7,  lw = rr - lh * 7;
            const int t0 = (it * 8 + lt + 4) & 15;
            int h0 = ih * 7 + lh + 3; if (h0 >= 56) h0 -= 56;
            int w0 = iw * 7 + lw + 3; if (w0 >= 56) w0 -= 56;
            const float* xp = x + (size_t)(((b * 16 + t0) * 56 + h0) * 56 + w0) * DIMC + 8 * lg;
#pragma unroll
            for (int ks = 0; ks < 4; ++ks)
                af[ks] = pack8(*(const float4*)(xp + ks * 32),
                               *(const float4*)(xp + ks * 32 + 4));
        } else {
#pragma unroll
            for (int ks = 0; ks < 4; ++ks) af[ks] = zero8();
        }
        // Q (o=0,1) and K (o=2,3): C rows = token, cols = head-dim
#pragma unroll
        for (int o = 0; o < 4; ++o) {
            f32x4 acc = {0.f, 0.f, 0.f, 0.f};
#pragma unroll
            for (int ks = 0; ks < 4; ++ks)
                acc = __builtin_amdgcn_mfma_f32_16x16x32_bf16(af[ks], wfr[o][ks], acc, 0, 0, 0);
            bf16* dst = lds + ((o < 2) ? OFF_Q : OFF_K);
            const float sc = (o < 2) ? SCALE : 1.0f;
            const int cb = (o & 1) * 16 + l16;
#pragma unroll
            for (int r = 0; r < 4; ++r) {
                const int row = mt * 16 + lg * 4 + r;
                if (row < VOL)
                    dst[row * 32 + (cb ^ (swz4(row) << 3))] = (bf16)((acc[r] + bcol[o]) * sc);
            }
        }
        // V^T: C rows = head-dim n, cols = token  (A=W, B=x)
        // NOTE: must cover ALL tv in [0,416) — swizzled slots for tv>=400
        // would otherwise stay uninitialized and 0 x NaN = NaN in PV MFMA.
#pragma unroll
        for (int h2 = 0; h2 < 2; ++h2) {
            f32x4 acc = {0.f, 0.f, 0.f, 0.f};
#pragma unroll
            for (int ks = 0; ks < 4; ++ks)
                acc = __builtin_amdgcn_mfma_f32_16x16x32_bf16(wfr[4 + h2][ks], af[ks], acc, 0, 0, 0);
#pragma unroll
            for (int r = 0; r < 4; ++r) {
                const int n = h2 * 16 + lg * 4 + r;
                lds[OFF_VT + n * VTCOLS + (tv ^ (swz4(n) << 3))] = (bf16)(acc[r] + bvr[h2][r]);
            }
        }
    }
    __syncthreads();

    // ---------------- phase 2: S^T = mfma(K, Q, bias) ----------------------
    for (int mt = wv; mt < 25; mt += 4) {
        const int qtok = mt * 16 + l16;
        const int qr   = (qtok < QROWS) ? qtok : (QROWS - 1);
        const bf16x8 qf = *(const bf16x8*)&lds[OFF_Q + qr * 32 + ((lg * 8) ^ (swz4(qr) << 3))];
        const bf16* trow = tblh + (size_t)qtok * TK;

        f32x4 s[26];
#pragma unroll
        for (int nt = 0; nt < 26; ++nt) {
            const int ktok = nt * 16 + l16;
            const int kr   = (ktok < QROWS) ? ktok : (QROWS - 1);
            const bf16x8 kf = *(const bf16x8*)&lds[OFF_K + kr * 32 + ((lg * 8) ^ (swz4(kr) << 3))];
            const bf16x4 bb = *(const bf16x4*)&trow[nt * 16 + lg * 4];
            f32x4 c;
#pragma unroll
            for (int r = 0; r < 4; ++r) c[r] = (float)bb[r];
            // C layout: row = k (lg*4+r), col = q (l16)
            s[nt] = __builtin_amdgcn_mfma_f32_16x16x32_bf16(kf, qf, c, 0, 0, 0);
        }
        // softmax over k: per-lane partial (26 nt x 4 r), then reduce lg groups
        float mx = -1e30f;
#pragma unroll
        for (int nt = 0; nt < 26; ++nt)
#pragma unroll
            for (int r = 0; r < 4; ++r) mx = fmaxf(mx, s[nt][r]);
        mx = fmaxf(mx, __shfl_xor(mx, 16));
        mx = fmaxf(mx, __shfl_xor(mx, 32));
        float sum = 0.f;
#pragma unroll
        for (int nt = 0; nt < 26; ++nt)
#pragma unroll
            for (int r = 0; r < 4; ++r) {
                const float e = __expf(s[nt][r] - mx);
                s[nt][r] = e; sum += e;
            }
        sum += __shfl_xor(sum, 16);
        sum += __shfl_xor(sum, 32);
        const float inv = 1.0f / sum;

        // PV: O^T = mfma(V^T, P)  (A rows = n, B cols = q)
        f32x4 o0 = {0.f, 0.f, 0.f, 0.f}, o1 = {0.f, 0.f, 0.f, 0.f};
#pragma unroll
        for (int ch = 0; ch < 13; ++ch) {
#pragma unroll
            for (int sub = 0; sub < 2; ++sub) {
                bf16x4 p;
#pragma unroll
                for (int r = 0; r < 4; ++r) p[r] = (bf16)(s[2 * ch + sub][r] * inv);
                *(bf16x4*)&pst[l16 * PSTR + sub * 16 + lg * 4] = p;   // P^T -> [q][k] stage
            }
            asm volatile("s_waitcnt lgkmcnt(0)" ::: "memory");
            const bf16x4 p0 = *(const bf16x4*)&pst[l16 * PSTR + lg * 8];
            const bf16x4 p1 = *(const bf16x4*)&pst[l16 * PSTR + lg * 8 + 4];
            const bf16x8 pf = cat8(p0, p1);
            const int n0 = l16, n1 = 16 + l16;
            const bf16x8 v0 = *(const bf16x8*)&lds[OFF_VT + n0 * VTCOLS + ((ch * 32 + lg * 8) ^ (swz4(n0) << 3))];
            const bf16x8 v1 = *(const bf16x8*)&lds[OFF_VT + n1 * VTCOLS + ((ch * 32 + lg * 8) ^ (swz4(n1) << 3))];
            o0 = __builtin_amdgcn_mfma_f32_16x16x32_bf16(v0, pf, o0, 0, 0, 0);
            o1 = __builtin_amdgcn_mfma_f32_16x16x32_bf16(v1, pf, o1, 0, 0, 0);
        }
        if (qtok < VOL) {
            bf16x4 w0, w1;
#pragma unroll
            for (int r = 0; r < 4; ++r) { w0[r] = (bf16)o0[r]; w1[r] = (bf16)o1[r]; }
            bf16* op = aw + ((size_t)win * VPAD + qtok) * DIMC + head * HD + lg * 4;
            *(bf16x4*)op = w0;
            *(bf16x4*)(op + 16) = w1;
        }
    }
}

// ---------------------------------------------------------------------------
// Kernel B: per window: proj GEMM + inverse-shift scatter -> out (f32)
// ---------------------------------------------------------------------------
__global__ __launch_bounds__(256, 1) void swin_proj(
    const bf16* __restrict__ aw, const float* __restrict__ wproj,
    const float* __restrict__ bproj, float* __restrict__ out)
{
    const int win  = blockIdx.x;
    const int b    = win >> 7;
    const int wrem = win & 127;
    const int it   = wrem >> 6;
    const int ih   = (wrem >> 3) & 7;
    const int iw   = wrem & 7;

    const int tid  = threadIdx.x;
    const int lane = tid & 63;
    const int wv   = tid >> 6;
    const int l16  = lane & 15;
    const int lg   = lane >> 4;

    for (int mt = wv; mt < 25; mt += 4) {
        bf16x8 af[4];
        const bf16* ap = aw + ((size_t)win * VPAD + mt * 16 + l16) * DIMC + 8 * lg;
#pragma unroll
        for (int ks = 0; ks < 4; ++ks) af[ks] = *(const bf16x8*)(ap + ks * 32);

        float* ob[4]; bool qok[4];
#pragma unroll
        for (int r = 0; r < 4; ++r) {
            int q = mt * 16 + lg * 4 + r;
            qok[r] = q < VOL; if (!qok[r]) q = 0;
            const int lt = q / 49, rr = q - lt * 49;
            const int lh = rr / 7, lw = rr - lh * 7;
            const int t0 = (it * 8 + lt + 4) & 15;
            int h0 = ih * 7 + lh + 3; if (h0 >= 56) h0 -= 56;
            int w0 = iw * 7 + lw + 3; if (w0 >= 56) w0 -= 56;
            ob[r] = out + (size_t)(((b * 16 + t0) * 56 + h0) * 56 + w0) * DIMC;
        }
#pragma unroll
        for (int nt = 0; nt < 8; ++nt) {
            f32x4 acc = {0.f, 0.f, 0.f, 0.f};
            const float* wp = wproj + (size_t)(nt * 16 + l16) * DIMC + 8 * lg;
#pragma unroll
            for (int ks = 0; ks < 4; ++ks) {
                float4 u0 = *(const float4*)(wp + ks * 32);
                float4 u1 = *(const float4*)(wp + ks * 32 + 4);
                acc = __builtin_amdgcn_mfma_f32_16x16x32_bf16(af[ks], pack8(u0, u1), acc, 0, 0, 0);
            }
            const float bv = bproj[nt * 16 + l16];
#pragma unroll
            for (int r = 0; r < 4; ++r)
                if (qok[r]) ob[r][nt * 16 + l16] = acc[r] + bv;
        }
    }
}

extern "C" void kernel_launch(void* const* d_in, const int* in_sizes, int n_in,
                              void* d_out, int out_size, void* d_ws, size_t ws_size,
                              hipStream_t stream) {
    const float* x     = (const float*)d_in[0];
    const float* wqkv  = (const float*)d_in[1];
    const float* bqkv  = (const float*)d_in[2];
    const float* wproj = (const float*)d_in[3];
    const float* bproj = (const float*)d_in[4];
    const float* btab  = (const float*)d_in[5];
    bf16*  aw  = (bf16*)d_ws;                                  // 27.26 MB
    bf16*  tbl = (bf16*)((char*)d_ws + AW_BYTES);              // 10.65 MB
    float* out = (float*)d_out;

    (void)hipFuncSetAttribute((const void*)swin_attn,
                              hipFuncAttributeMaxDynamicSharedMemorySize, SMEM_A);

    const int tbl_threads = 8 * HEADS * TQ * (TK / 4);
    gen_table<<<dim3((tbl_threads + 255) / 256), dim3(256), 0, stream>>>(btab, tbl);
    swin_attn<<<dim3(256 * HEADS), dim3(256), SMEM_A, stream>>>(x, wqkv, bqkv, tbl, aw);
    swin_proj<<<dim3(256), dim3(256), 0, stream>>>(aw, wproj, bproj, out);
}